// Round 11
// baseline (83.751 us; speedup 1.0000x reference)
//
#include <hip/hip_runtime.h>
#include <stdint.h>

__device__ __forceinline__ float sgnf(float v) {
    return (v > 0.f) ? 1.f : ((v < 0.f) ? -1.f : 0.f);
}

// ---------------------------------------------------------------------------
// Prep: w1q = sign(W1) as float, so the main kernel can load weights via
// block-uniform (scalarizable) loads in the conv loop.
// ---------------------------------------------------------------------------
__global__ void prep_w1(const float* __restrict__ W1, float* __restrict__ w1q) {
    const int i = blockIdx.x * 256 + threadIdx.x;
    if (i < 250000) w1q[i] = sgnf(W1[i]);
}

// ---------------------------------------------------------------------------
// Fused kernel: one block = 8 channels (1250 blocks), R10 structure.
// Binarize is done via the exact threshold identity:
//   sign(leakyrelu(y) - 0.5) == (y > 0.5 ? 1 : (y < 0.5 ? -1 : 0))
// (for y>0 the subtraction y-0.5 has the exact sign of y-0.5 by Sterbenz /
// monotone rounding; for y<=0 both sides are -1). This is bit-identical to
// the verified absmax-0.0 lineage while saving ~4 VALU/element.
// The final /100 scale is folded into the per-block class partials
// (each partial is an exact small integer; 625 rounded k/100 terms differ
// from a single rounding by <=~1e-5, threshold is 6.4e-2).
// ---------------------------------------------------------------------------
__global__ __launch_bounds__(256, 2) void hdc_fused(
    const float* __restrict__ x,  const float* __restrict__ w1q,
    const float* __restrict__ b1, const float* __restrict__ g1,
    const float* __restrict__ be1,
    const float* __restrict__ W2, const float* __restrict__ b2,
    const float* __restrict__ g2, const float* __restrict__ be2,
    const float* __restrict__ W3, const float* __restrict__ b3,
    const float* __restrict__ g3, const float* __restrict__ be3,
    const float* __restrict__ Wc, const float* __restrict__ zrow,
    float* __restrict__ out)
{
    __shared__ signed char h1s[8 * 2704];   // 21632 B
    __shared__ float redbuf[2][4][8];       // [sweep][wave][mean0..3|var0..3]
    __shared__ float h3buf[8 * 16];

    const int tid  = threadIdx.x;
    const int base = blockIdx.x * 8;

    const bool act = (tid < 208);
    const int oy = tid >> 4, bb = tid & 15;
    const int wv = tid >> 6, ln = tid & 63;

    // ---- conv1 + BN1 + binarize: two sweeps of 4 channels ----
    for (int sg = 0; sg < 2; ++sg) {
        const int d0 = base + 4 * sg;
        const float* __restrict__ wp = w1q + d0 * 25;   // block-uniform

        float acc[4][13];
        #pragma unroll
        for (int c = 0; c < 4; ++c) {
            const float bv = b1[d0 + c];
            #pragma unroll
            for (int i = 0; i < 13; ++i) acc[c][i] = bv;
        }

        if (act) {
            #pragma unroll
            for (int ky = 0; ky < 5; ++ky) {
                const int rr_ = 2 * oy - 1 + ky;           // -1..27
                const float* rp = (rr_ >= 0) ? (x + bb * 784 + rr_ * 28) : zrow;
                float r[29];
                r[0] = 0.f;                                 // col -1 pad
                #pragma unroll
                for (int j = 0; j < 7; ++j) {
                    float4 v = ((const float4*)rp)[j];
                    r[4 * j + 1] = v.x; r[4 * j + 2] = v.y;
                    r[4 * j + 3] = v.z; r[4 * j + 4] = v.w;
                }
                #pragma unroll
                for (int kx = 0; kx < 5; ++kx) {
                    #pragma unroll
                    for (int c = 0; c < 4; ++c) {
                        const float wk = wp[c * 25 + 5 * ky + kx];
                        #pragma unroll
                        for (int ox = 0; ox < 13; ++ox)
                            acc[c][ox] = fmaf(r[2 * ox + kx], wk, acc[c][ox]);
                    }
                }
            }
        }

        // pass 1: means (identical reduction order to verified kernels)
        {
            float s[4] = {0.f, 0.f, 0.f, 0.f};
            if (act) {
                #pragma unroll
                for (int c = 0; c < 4; ++c)
                    #pragma unroll
                    for (int i = 0; i < 13; ++i) s[c] += acc[c][i];
            }
            #pragma unroll
            for (int m = 32; m >= 1; m >>= 1)
                #pragma unroll
                for (int c = 0; c < 4; ++c) s[c] += __shfl_xor(s[c], m, 64);
            if (ln == 0) {
                #pragma unroll
                for (int c = 0; c < 4; ++c) redbuf[sg][wv][c] = s[c];
            }
        }
        __syncthreads();
        float mu[4];
        #pragma unroll
        for (int c = 0; c < 4; ++c)
            mu[c] = (redbuf[sg][0][c] + redbuf[sg][1][c]
                   + redbuf[sg][2][c] + redbuf[sg][3][c]) / 2704.f;

        // pass 2: variances (two-pass, mirrors jnp.var)
        {
            float dv[4] = {0.f, 0.f, 0.f, 0.f};
            if (act) {
                #pragma unroll
                for (int c = 0; c < 4; ++c) {
                    #pragma unroll
                    for (int i = 0; i < 13; ++i) {
                        const float e = acc[c][i] - mu[c];
                        dv[c] = fmaf(e, e, dv[c]);
                    }
                }
            }
            #pragma unroll
            for (int m = 32; m >= 1; m >>= 1)
                #pragma unroll
                for (int c = 0; c < 4; ++c) dv[c] += __shfl_xor(dv[c], m, 64);
            if (ln == 0) {
                #pragma unroll
                for (int c = 0; c < 4; ++c) redbuf[sg][wv][4 + c] = dv[c];
            }
        }
        __syncthreads();

        // binarize 4 channels into LDS via threshold compare (bit-exact)
        float iv[4];
        #pragma unroll
        for (int c = 0; c < 4; ++c)
            iv[c] = rsqrtf((redbuf[sg][0][4 + c] + redbuf[sg][1][4 + c]
                          + redbuf[sg][2][4 + c] + redbuf[sg][3][4 + c]) / 2704.f + 1e-5f);
        if (act) {
            #pragma unroll
            for (int c = 0; c < 4; ++c) {
                const float ga = g1[d0 + c], bea = be1[d0 + c];
                signed char* hp = &h1s[(4 * sg + c) * 2704 + bb * 169 + oy * 13];
                #pragma unroll
                for (int i = 0; i < 13; ++i) {
                    const float xn = (acc[c][i] - mu[c]) * iv[c];
                    const float y  = fmaf(xn, ga, bea);
                    hp[i] = (y > 0.5f) ? 1 : ((y < 0.5f) ? -1 : 0);
                }
            }
        }
    }
    __syncthreads();   // h1s complete for all 8 channels

    // ---- tail: conv2 + BN2 + sign + conv3 + BN3 + sign (proven structure) ----
    if (tid < 128) {
        const int ch = tid >> 4, b_ = tid & 15;
        const int d = base + ch;
        float sw2[9];
        #pragma unroll
        for (int k = 0; k < 9; ++k) sw2[k] = sgnf(W2[d * 9 + k]);
        const float b2v = b2[d];
        const signed char* hp = &h1s[ch * 2704 + b_ * 169];

        float c2[36];
        #pragma unroll
        for (int oy2 = 0; oy2 < 6; ++oy2) {
            float rr[3][13];
            #pragma unroll
            for (int ky = 0; ky < 3; ++ky)
                #pragma unroll
                for (int j = 0; j < 13; ++j)
                    rr[ky][j] = (float)hp[(2 * oy2 + ky) * 13 + j];
            #pragma unroll
            for (int ox2 = 0; ox2 < 6; ++ox2) {
                float s = b2v;
                #pragma unroll
                for (int ky = 0; ky < 3; ++ky)
                    #pragma unroll
                    for (int kx = 0; kx < 3; ++kx)
                        s = fmaf(rr[ky][2 * ox2 + kx], sw2[3 * ky + kx], s);
                c2[oy2 * 6 + ox2] = s;
            }
        }

        // BN2 over (b, 6, 6): exact small integers
        float s2 = 0.f;
        #pragma unroll
        for (int i = 0; i < 36; ++i) s2 += c2[i];
        #pragma unroll
        for (int m = 8; m >= 1; m >>= 1) s2 += __shfl_xor(s2, m, 16);
        const float mu2 = s2 / 576.f;
        float d2 = 0.f;
        #pragma unroll
        for (int i = 0; i < 36; ++i) { const float e = c2[i] - mu2; d2 = fmaf(e, e, d2); }
        #pragma unroll
        for (int m = 8; m >= 1; m >>= 1) d2 += __shfl_xor(d2, m, 16);
        const float inv2 = rsqrtf(d2 / 576.f + 1e-5f);
        const float g2v = g2[d], be2v = be2[d];

        // binarize h2 (threshold compare) fused into conv3
        float z3 = b3[d];
        #pragma unroll
        for (int i = 0; i < 36; ++i) {
            const float xn = (c2[i] - mu2) * inv2;
            const float y  = fmaf(xn, g2v, be2v);
            const float h2 = (y > 0.5f) ? 1.f : ((y < 0.5f) ? -1.f : 0.f);
            z3 = fmaf(h2, W3[d * 36 + i], z3);
        }

        // BN3 over batch (16 lanes)
        float s3 = z3;
        #pragma unroll
        for (int m = 8; m >= 1; m >>= 1) s3 += __shfl_xor(s3, m, 16);
        const float mu3 = s3 / 16.f;
        const float e3 = z3 - mu3;
        float d3 = e3 * e3;
        #pragma unroll
        for (int m = 8; m >= 1; m >>= 1) d3 += __shfl_xor(d3, m, 16);
        const float inv3 = rsqrtf(d3 / 16.f + 1e-5f);
        const float xn3 = (z3 - mu3) * inv3;
        const float y3  = fmaf(xn3, g3[d], be3[d]);
        h3buf[tid] = (y3 > 0.5f) ? 1.f : ((y3 < 0.5f) ? -1.f : 0.f);
    }
    __syncthreads();

    // ---- per-block class partials (exact small ints), scaled by 1/100 ----
    if (tid < 160) {
        const int bq = tid / 10, cq = tid - bq * 10;
        float ssum = 0.f;
        #pragma unroll
        for (int ch = 0; ch < 8; ++ch)
            ssum += h3buf[ch * 16 + bq] * sgnf(Wc[cq * 10000 + base + ch]);
        atomicAdd(&out[bq * 10 + cq], ssum / 100.0f);
    }
}

extern "C" void kernel_launch(void* const* d_in, const int* in_sizes, int n_in,
                              void* d_out, int out_size, void* d_ws, size_t ws_size,
                              hipStream_t stream) {
    const float* x   = (const float*)d_in[0];
    const float* W1  = (const float*)d_in[1];
    const float* b1  = (const float*)d_in[2];
    const float* g1  = (const float*)d_in[3];
    const float* be1 = (const float*)d_in[4];
    const float* W2  = (const float*)d_in[5];
    const float* b2  = (const float*)d_in[6];
    const float* g2  = (const float*)d_in[7];
    const float* be2 = (const float*)d_in[8];
    const float* W3  = (const float*)d_in[9];
    const float* b3  = (const float*)d_in[10];
    const float* g3  = (const float*)d_in[11];
    const float* be3 = (const float*)d_in[12];
    const float* Wc  = (const float*)d_in[13];
    float* out  = (float*)d_out;
    float* w1q  = (float*)d_ws;                  // 250000 floats = 1 MB
    float* zrow = (float*)d_ws + 250000;         // 112 B of zeros (row -1 pad)

    hipMemsetAsync(out, 0, 160 * sizeof(float), stream);
    hipMemsetAsync(zrow, 0, 128, stream);

    prep_w1<<<dim3(977), dim3(256), 0, stream>>>(W1, w1q);
    hdc_fused<<<dim3(1250), dim3(256), 0, stream>>>(
        x, w1q, b1, g1, be1, W2, b2, g2, be2, W3, b3, g3, be3, Wc, zrow, out);
}

// Round 12
// 74.531 us; speedup vs baseline: 1.1237x; 1.1237x over previous
//
#include <hip/hip_runtime.h>
#include <stdint.h>

__device__ __forceinline__ float sgnf(float v) {
    return (v > 0.f) ? 1.f : ((v < 0.f) ? -1.f : 0.f);
}

// ---------------------------------------------------------------------------
// Prep: w1q = sign(W1); also zeroes out[] and zrow (replaces two memsets).
// ---------------------------------------------------------------------------
__global__ void prep_w1(const float* __restrict__ W1, float* __restrict__ w1q,
                        float* __restrict__ out, float* __restrict__ zrow) {
    const int i = blockIdx.x * 256 + threadIdx.x;
    if (i < 250000) w1q[i] = sgnf(W1[i]);
    if (blockIdx.x == 0) {
        if (threadIdx.x < 160) out[threadIdx.x] = 0.f;
        else if (threadIdx.x < 192) zrow[threadIdx.x - 160] = 0.f;
    }
}

// ---------------------------------------------------------------------------
// Fused kernel, grid = 1024 blocks == exactly the 4-blocks/CU residency
// capacity (VGPR pool: 16 waves/CU at 65..128 regs):
//   blocks [0,452):  12 channels, 3 sweeps of 4   (heavy, dispatched first)
//   blocks [452,1024): 8 channels, 2 sweeps of 4
// Sweep body identical to the verified R10 absmax-0.0 kernel: same conv
// order (ky->kx->c->ox), same 13-sum + 6-level shuffle + 4-wave fold, same
// two-pass variance, same binarize. Class partials are exact small ints,
// scaled by 1/100 per block (error ~1e-6, threshold 6.4e-2).
// ---------------------------------------------------------------------------
__global__ __launch_bounds__(256, 2) void hdc_fused(
    const float* __restrict__ x,  const float* __restrict__ w1q,
    const float* __restrict__ b1, const float* __restrict__ g1,
    const float* __restrict__ be1,
    const float* __restrict__ W2, const float* __restrict__ b2,
    const float* __restrict__ g2, const float* __restrict__ be2,
    const float* __restrict__ W3, const float* __restrict__ b3,
    const float* __restrict__ g3, const float* __restrict__ be3,
    const float* __restrict__ Wc, const float* __restrict__ zrow,
    float* __restrict__ out)
{
    __shared__ signed char h1s[12 * 2704];  // 32448 B (heavy-block max)
    __shared__ float redbuf[3][4][8];       // [sweep][wave][mean0..3|var0..3]
    __shared__ float h3buf[12 * 16];
    __shared__ float wcs[120];              // sign(Wc) slice: [ch][cls]

    const int tid = threadIdx.x;
    const bool heavy = (blockIdx.x < 452);
    const int nch  = heavy ? 12 : 8;
    const int nsw  = heavy ? 3 : 2;
    const int base = heavy ? blockIdx.x * 12 : 5424 + (blockIdx.x - 452) * 8;

    const bool act = (tid < 208);
    const int oy = tid >> 4, bb = tid & 15;
    const int wv = tid >> 6, ln = tid & 63;

    // ---- conv1 + BN1 + binarize: nsw sweeps of 4 channels ----
    for (int sg = 0; sg < nsw; ++sg) {
        const int d0 = base + 4 * sg;
        const float* __restrict__ wp = w1q + d0 * 25;   // block-uniform

        float acc[4][13];
        #pragma unroll
        for (int c = 0; c < 4; ++c) {
            const float bv = b1[d0 + c];
            #pragma unroll
            for (int i = 0; i < 13; ++i) acc[c][i] = bv;
        }

        if (act) {
            #pragma unroll
            for (int ky = 0; ky < 5; ++ky) {
                const int rr_ = 2 * oy - 1 + ky;           // -1..27
                const float* rp = (rr_ >= 0) ? (x + bb * 784 + rr_ * 28) : zrow;
                float r[29];
                r[0] = 0.f;                                 // col -1 pad
                #pragma unroll
                for (int j = 0; j < 7; ++j) {
                    float4 v = ((const float4*)rp)[j];
                    r[4 * j + 1] = v.x; r[4 * j + 2] = v.y;
                    r[4 * j + 3] = v.z; r[4 * j + 4] = v.w;
                }
                #pragma unroll
                for (int kx = 0; kx < 5; ++kx) {
                    #pragma unroll
                    for (int c = 0; c < 4; ++c) {
                        const float wk = wp[c * 25 + 5 * ky + kx];
                        #pragma unroll
                        for (int ox = 0; ox < 13; ++ox)
                            acc[c][ox] = fmaf(r[2 * ox + kx], wk, acc[c][ox]);
                    }
                }
            }
        }

        // pass 1: means (identical reduction order to verified kernels)
        {
            float s[4] = {0.f, 0.f, 0.f, 0.f};
            if (act) {
                #pragma unroll
                for (int c = 0; c < 4; ++c)
                    #pragma unroll
                    for (int i = 0; i < 13; ++i) s[c] += acc[c][i];
            }
            #pragma unroll
            for (int m = 32; m >= 1; m >>= 1)
                #pragma unroll
                for (int c = 0; c < 4; ++c) s[c] += __shfl_xor(s[c], m, 64);
            if (ln == 0) {
                #pragma unroll
                for (int c = 0; c < 4; ++c) redbuf[sg][wv][c] = s[c];
            }
        }
        __syncthreads();
        float mu[4];
        #pragma unroll
        for (int c = 0; c < 4; ++c)
            mu[c] = (redbuf[sg][0][c] + redbuf[sg][1][c]
                   + redbuf[sg][2][c] + redbuf[sg][3][c]) / 2704.f;

        // pass 2: variances (two-pass, mirrors jnp.var)
        {
            float dv[4] = {0.f, 0.f, 0.f, 0.f};
            if (act) {
                #pragma unroll
                for (int c = 0; c < 4; ++c) {
                    #pragma unroll
                    for (int i = 0; i < 13; ++i) {
                        const float e = acc[c][i] - mu[c];
                        dv[c] = fmaf(e, e, dv[c]);
                    }
                }
            }
            #pragma unroll
            for (int m = 32; m >= 1; m >>= 1)
                #pragma unroll
                for (int c = 0; c < 4; ++c) dv[c] += __shfl_xor(dv[c], m, 64);
            if (ln == 0) {
                #pragma unroll
                for (int c = 0; c < 4; ++c) redbuf[sg][wv][4 + c] = dv[c];
            }
        }
        __syncthreads();

        // binarize 4 channels into LDS (no trailing barrier: next sweep
        // uses a different redbuf buffer; h1s regions are disjoint)
        float iv[4];
        #pragma unroll
        for (int c = 0; c < 4; ++c)
            iv[c] = rsqrtf((redbuf[sg][0][4 + c] + redbuf[sg][1][4 + c]
                          + redbuf[sg][2][4 + c] + redbuf[sg][3][4 + c]) / 2704.f + 1e-5f);
        if (act) {
            #pragma unroll
            for (int c = 0; c < 4; ++c) {
                const float ga = g1[d0 + c], bea = be1[d0 + c];
                signed char* hp = &h1s[(4 * sg + c) * 2704 + bb * 169 + oy * 13];
                #pragma unroll
                for (int i = 0; i < 13; ++i) {
                    const float xn = (acc[c][i] - mu[c]) * iv[c];
                    const float y  = fmaf(xn, ga, bea);
                    const float z  = ((y > 0.f) ? y : 0.01f * y) - 0.5f;
                    hp[i] = (z > 0.f) ? 1 : ((z < 0.f) ? -1 : 0);
                }
            }
        }
    }
    __syncthreads();   // h1s complete for all channels

    // ---- tail: conv2 + BN2 + sign + conv3 + BN3 + sign (proven structure) ----
    if (tid < 16 * nch) {
        const int ch = tid >> 4, b_ = tid & 15;
        const int d = base + ch;
        float sw2[9];
        #pragma unroll
        for (int k = 0; k < 9; ++k) sw2[k] = sgnf(W2[d * 9 + k]);
        const float b2v = b2[d];
        const signed char* hp = &h1s[ch * 2704 + b_ * 169];

        float c2[36];
        #pragma unroll
        for (int oy2 = 0; oy2 < 6; ++oy2) {
            float rr[3][13];
            #pragma unroll
            for (int ky = 0; ky < 3; ++ky)
                #pragma unroll
                for (int j = 0; j < 13; ++j)
                    rr[ky][j] = (float)hp[(2 * oy2 + ky) * 13 + j];
            #pragma unroll
            for (int ox2 = 0; ox2 < 6; ++ox2) {
                float s = b2v;
                #pragma unroll
                for (int ky = 0; ky < 3; ++ky)
                    #pragma unroll
                    for (int kx = 0; kx < 3; ++kx)
                        s = fmaf(rr[ky][2 * ox2 + kx], sw2[3 * ky + kx], s);
                c2[oy2 * 6 + ox2] = s;
            }
        }

        // BN2 over (b, 6, 6): exact small integers
        float s2 = 0.f;
        #pragma unroll
        for (int i = 0; i < 36; ++i) s2 += c2[i];
        #pragma unroll
        for (int m = 8; m >= 1; m >>= 1) s2 += __shfl_xor(s2, m, 16);
        const float mu2 = s2 / 576.f;
        float d2 = 0.f;
        #pragma unroll
        for (int i = 0; i < 36; ++i) { const float e = c2[i] - mu2; d2 = fmaf(e, e, d2); }
        #pragma unroll
        for (int m = 8; m >= 1; m >>= 1) d2 += __shfl_xor(d2, m, 16);
        const float inv2 = rsqrtf(d2 / 576.f + 1e-5f);
        const float g2v = g2[d], be2v = be2[d];

        // binarize h2 fused into conv3
        float z3 = b3[d];
        #pragma unroll
        for (int i = 0; i < 36; ++i) {
            const float xn = (c2[i] - mu2) * inv2;
            const float y  = fmaf(xn, g2v, be2v);
            const float z  = ((y > 0.f) ? y : 0.01f * y) - 0.5f;
            const float h2 = (z > 0.f) ? 1.f : ((z < 0.f) ? -1.f : 0.f);
            z3 = fmaf(h2, W3[d * 36 + i], z3);
        }

        // BN3 over batch (16 lanes)
        float s3 = z3;
        #pragma unroll
        for (int m = 8; m >= 1; m >>= 1) s3 += __shfl_xor(s3, m, 16);
        const float mu3 = s3 / 16.f;
        const float e3 = z3 - mu3;
        float d3 = e3 * e3;
        #pragma unroll
        for (int m = 8; m >= 1; m >>= 1) d3 += __shfl_xor(d3, m, 16);
        const float inv3 = rsqrtf(d3 / 16.f + 1e-5f);
        const float xn3 = (z3 - mu3) * inv3;
        const float y3  = fmaf(xn3, g3[d], be3[d]);
        const float zz  = ((y3 > 0.f) ? y3 : 0.01f * y3) - 0.5f;
        h3buf[tid] = (zz > 0.f) ? 1.f : ((zz < 0.f) ? -1.f : 0.f);
    } else if (tid >= 192) {
        // tail-idle threads prefetch sign(Wc) slice into LDS: wcs[ch*10+cls]
        for (int i = tid - 192; i < 10 * nch; i += 64)
            wcs[i] = sgnf(Wc[(i % 10) * 10000 + base + (i / 10)]);
    }
    __syncthreads();

    // ---- per-block class partials (exact small ints), scaled by 1/100 ----
    if (tid < 160) {
        const int bq = tid / 10, cq = tid - bq * 10;
        float ssum = 0.f;
        for (int ch = 0; ch < nch; ++ch)
            ssum += h3buf[ch * 16 + bq] * wcs[ch * 10 + cq];
        atomicAdd(&out[bq * 10 + cq], ssum / 100.0f);
    }
}

extern "C" void kernel_launch(void* const* d_in, const int* in_sizes, int n_in,
                              void* d_out, int out_size, void* d_ws, size_t ws_size,
                              hipStream_t stream) {
    const float* x   = (const float*)d_in[0];
    const float* W1  = (const float*)d_in[1];
    const float* b1  = (const float*)d_in[2];
    const float* g1  = (const float*)d_in[3];
    const float* be1 = (const float*)d_in[4];
    const float* W2  = (const float*)d_in[5];
    const float* b2  = (const float*)d_in[6];
    const float* g2  = (const float*)d_in[7];
    const float* be2 = (const float*)d_in[8];
    const float* W3  = (const float*)d_in[9];
    const float* b3  = (const float*)d_in[10];
    const float* g3  = (const float*)d_in[11];
    const float* be3 = (const float*)d_in[12];
    const float* Wc  = (const float*)d_in[13];
    float* out  = (float*)d_out;
    float* w1q  = (float*)d_ws;                  // 250000 floats = 1 MB
    float* zrow = (float*)d_ws + 250000;         // 32 floats of zeros

    prep_w1<<<dim3(977), dim3(256), 0, stream>>>(W1, w1q, out, zrow);
    hdc_fused<<<dim3(1024), dim3(256), 0, stream>>>(
        x, w1q, b1, g1, be1, W2, b2, g2, be2, W3, b3, g3, be3, Wc, zrow, out);
}

// Round 13
// 73.383 us; speedup vs baseline: 1.1413x; 1.0156x over previous
//
#include <hip/hip_runtime.h>
#include <stdint.h>

#define H1B 176          // padded bytes per (ch,b) row in LDS (16B aligned)
#define H1C 2816         // bytes per channel (16 batches)

__device__ __forceinline__ float sgnf(float v) {
    return (v > 0.f) ? 1.f : ((v < 0.f) ? -1.f : 0.f);
}

// ---------------------------------------------------------------------------
// Prep: w1q = sign(W1); also zeroes out[] and zrow (replaces two memsets).
// ---------------------------------------------------------------------------
__global__ void prep_w1(const float* __restrict__ W1, float* __restrict__ w1q,
                        float* __restrict__ out, float* __restrict__ zrow) {
    const int i = blockIdx.x * 256 + threadIdx.x;
    if (i < 250000) w1q[i] = sgnf(W1[i]);
    if (blockIdx.x == 0) {
        if (threadIdx.x < 160) out[threadIdx.x] = 0.f;
        else if (threadIdx.x < 192) zrow[threadIdx.x - 160] = 0.f;
    }
}

// ---------------------------------------------------------------------------
// Fused kernel, grid = 1024 blocks (exact residency packing):
//   blocks [0,452):   12 channels, 3 sweeps of 4  (heavy, dispatched first)
//   blocks [452,1024): 8 channels, 2 sweeps of 4
// Sweep body identical to the verified absmax-0.0 lineage. h1 LDS rows are
// padded to 176 B so the tail can use ds_read_b128 + in-register byte
// extraction (R2-k2's verified pattern) instead of 234 ds_read_u8/thread.
// Class partials are exact small ints scaled by 1/100 per block.
// ---------------------------------------------------------------------------
__global__ __launch_bounds__(256, 2) void hdc_fused(
    const float* __restrict__ x,  const float* __restrict__ w1q,
    const float* __restrict__ b1, const float* __restrict__ g1,
    const float* __restrict__ be1,
    const float* __restrict__ W2, const float* __restrict__ b2,
    const float* __restrict__ g2, const float* __restrict__ be2,
    const float* __restrict__ W3, const float* __restrict__ b3,
    const float* __restrict__ g3, const float* __restrict__ be3,
    const float* __restrict__ Wc, const float* __restrict__ zrow,
    float* __restrict__ out)
{
    __shared__ __align__(16) signed char h1s[12 * H1C];  // 33792 B
    __shared__ float redbuf[3][4][8];       // [sweep][wave][mean0..3|var0..3]
    __shared__ float h3buf[12 * 16];
    __shared__ float wcs[120];              // sign(Wc) slice: [ch][cls]

    const int tid = threadIdx.x;
    const bool heavy = (blockIdx.x < 452);
    const int nch  = heavy ? 12 : 8;
    const int nsw  = heavy ? 3 : 2;
    const int base = heavy ? blockIdx.x * 12 : 5424 + (blockIdx.x - 452) * 8;

    const bool act = (tid < 208);
    const int oy = tid >> 4, bb = tid & 15;
    const int wv = tid >> 6, ln = tid & 63;

    // ---- conv1 + BN1 + binarize: nsw sweeps of 4 channels ----
    for (int sg = 0; sg < nsw; ++sg) {
        const int d0 = base + 4 * sg;
        const float* __restrict__ wp = w1q + d0 * 25;   // block-uniform

        float acc[4][13];
        #pragma unroll
        for (int c = 0; c < 4; ++c) {
            const float bv = b1[d0 + c];
            #pragma unroll
            for (int i = 0; i < 13; ++i) acc[c][i] = bv;
        }

        if (act) {
            #pragma unroll
            for (int ky = 0; ky < 5; ++ky) {
                const int rr_ = 2 * oy - 1 + ky;           // -1..27
                const float* rp = (rr_ >= 0) ? (x + bb * 784 + rr_ * 28) : zrow;
                float r[29];
                r[0] = 0.f;                                 // col -1 pad
                #pragma unroll
                for (int j = 0; j < 7; ++j) {
                    float4 v = ((const float4*)rp)[j];
                    r[4 * j + 1] = v.x; r[4 * j + 2] = v.y;
                    r[4 * j + 3] = v.z; r[4 * j + 4] = v.w;
                }
                #pragma unroll
                for (int kx = 0; kx < 5; ++kx) {
                    #pragma unroll
                    for (int c = 0; c < 4; ++c) {
                        const float wk = wp[c * 25 + 5 * ky + kx];
                        #pragma unroll
                        for (int ox = 0; ox < 13; ++ox)
                            acc[c][ox] = fmaf(r[2 * ox + kx], wk, acc[c][ox]);
                    }
                }
            }
        }

        // pass 1: means (identical reduction order to verified kernels)
        {
            float s[4] = {0.f, 0.f, 0.f, 0.f};
            if (act) {
                #pragma unroll
                for (int c = 0; c < 4; ++c)
                    #pragma unroll
                    for (int i = 0; i < 13; ++i) s[c] += acc[c][i];
            }
            #pragma unroll
            for (int m = 32; m >= 1; m >>= 1)
                #pragma unroll
                for (int c = 0; c < 4; ++c) s[c] += __shfl_xor(s[c], m, 64);
            if (ln == 0) {
                #pragma unroll
                for (int c = 0; c < 4; ++c) redbuf[sg][wv][c] = s[c];
            }
        }
        __syncthreads();
        float mu[4];
        #pragma unroll
        for (int c = 0; c < 4; ++c)
            mu[c] = (redbuf[sg][0][c] + redbuf[sg][1][c]
                   + redbuf[sg][2][c] + redbuf[sg][3][c]) / 2704.f;

        // pass 2: variances (two-pass, mirrors jnp.var)
        {
            float dv[4] = {0.f, 0.f, 0.f, 0.f};
            if (act) {
                #pragma unroll
                for (int c = 0; c < 4; ++c) {
                    #pragma unroll
                    for (int i = 0; i < 13; ++i) {
                        const float e = acc[c][i] - mu[c];
                        dv[c] = fmaf(e, e, dv[c]);
                    }
                }
            }
            #pragma unroll
            for (int m = 32; m >= 1; m >>= 1)
                #pragma unroll
                for (int c = 0; c < 4; ++c) dv[c] += __shfl_xor(dv[c], m, 64);
            if (ln == 0) {
                #pragma unroll
                for (int c = 0; c < 4; ++c) redbuf[sg][wv][4 + c] = dv[c];
            }
        }
        __syncthreads();

        // binarize 4 channels into LDS (padded rows)
        float iv[4];
        #pragma unroll
        for (int c = 0; c < 4; ++c)
            iv[c] = rsqrtf((redbuf[sg][0][4 + c] + redbuf[sg][1][4 + c]
                          + redbuf[sg][2][4 + c] + redbuf[sg][3][4 + c]) / 2704.f + 1e-5f);
        if (act) {
            #pragma unroll
            for (int c = 0; c < 4; ++c) {
                const float ga = g1[d0 + c], bea = be1[d0 + c];
                signed char* hp = &h1s[(4 * sg + c) * H1C + bb * H1B + oy * 13];
                #pragma unroll
                for (int i = 0; i < 13; ++i) {
                    const float xn = (acc[c][i] - mu[c]) * iv[c];
                    const float y  = fmaf(xn, ga, bea);
                    const float z  = ((y > 0.f) ? y : 0.01f * y) - 0.5f;
                    hp[i] = (z > 0.f) ? 1 : ((z < 0.f) ? -1 : 0);
                }
            }
        }
    }
    __syncthreads();   // h1s complete for all channels

    // ---- tail: conv2 + BN2 + sign + conv3 + BN3 + sign ----
    if (tid < 16 * nch) {
        const int ch = tid >> 4, b_ = tid & 15;
        const int d = base + ch;

        // vectorized LDS read of the 169-byte row (aligned: 176-B stride)
        uint32_t u[44];
        {
            const uint4* hp4 = (const uint4*)&h1s[ch * H1C + b_ * H1B];
            #pragma unroll
            for (int j = 0; j < 11; ++j) {
                uint4 v = hp4[j];
                u[4 * j + 0] = v.x; u[4 * j + 1] = v.y;
                u[4 * j + 2] = v.z; u[4 * j + 3] = v.w;
            }
        }
#define HB(i) ((float)((signed char)(u[(i) >> 2] >> (((i) & 3) * 8))))

        float sw2[9];
        #pragma unroll
        for (int k = 0; k < 9; ++k) sw2[k] = sgnf(W2[d * 9 + k]);
        const float b2v = b2[d];

        float c2[36];
        #pragma unroll
        for (int oy2 = 0; oy2 < 6; ++oy2) {
            #pragma unroll
            for (int ox2 = 0; ox2 < 6; ++ox2) {
                float sacc = b2v;
                #pragma unroll
                for (int ky = 0; ky < 3; ++ky)
                    #pragma unroll
                    for (int kx = 0; kx < 3; ++kx)
                        sacc = fmaf(HB((2 * oy2 + ky) * 13 + 2 * ox2 + kx),
                                    sw2[3 * ky + kx], sacc);
                c2[oy2 * 6 + ox2] = sacc;
            }
        }
#undef HB

        // BN2 over (b, 6, 6): exact small integers
        float s2 = 0.f;
        #pragma unroll
        for (int i = 0; i < 36; ++i) s2 += c2[i];
        #pragma unroll
        for (int m = 8; m >= 1; m >>= 1) s2 += __shfl_xor(s2, m, 16);
        const float mu2 = s2 / 576.f;
        float d2 = 0.f;
        #pragma unroll
        for (int i = 0; i < 36; ++i) { const float e = c2[i] - mu2; d2 = fmaf(e, e, d2); }
        #pragma unroll
        for (int m = 8; m >= 1; m >>= 1) d2 += __shfl_xor(d2, m, 16);
        const float inv2 = rsqrtf(d2 / 576.f + 1e-5f);
        const float g2v = g2[d], be2v = be2[d];

        // binarize h2 fused into conv3
        float z3 = b3[d];
        #pragma unroll
        for (int i = 0; i < 36; ++i) {
            const float xn = (c2[i] - mu2) * inv2;
            const float y  = fmaf(xn, g2v, be2v);
            const float z  = ((y > 0.f) ? y : 0.01f * y) - 0.5f;
            const float h2 = (z > 0.f) ? 1.f : ((z < 0.f) ? -1.f : 0.f);
            z3 = fmaf(h2, W3[d * 36 + i], z3);
        }

        // BN3 over batch (16 lanes)
        float s3 = z3;
        #pragma unroll
        for (int m = 8; m >= 1; m >>= 1) s3 += __shfl_xor(s3, m, 16);
        const float mu3 = s3 / 16.f;
        const float e3 = z3 - mu3;
        float d3 = e3 * e3;
        #pragma unroll
        for (int m = 8; m >= 1; m >>= 1) d3 += __shfl_xor(d3, m, 16);
        const float inv3 = rsqrtf(d3 / 16.f + 1e-5f);
        const float xn3 = (z3 - mu3) * inv3;
        const float y3  = fmaf(xn3, g3[d], be3[d]);
        const float zz  = ((y3 > 0.f) ? y3 : 0.01f * y3) - 0.5f;
        h3buf[tid] = (zz > 0.f) ? 1.f : ((zz < 0.f) ? -1.f : 0.f);
    } else if (tid >= 192) {
        // tail-idle threads prefetch sign(Wc) slice into LDS: wcs[ch*10+cls]
        for (int i = tid - 192; i < 10 * nch; i += 64)
            wcs[i] = sgnf(Wc[(i % 10) * 10000 + base + (i / 10)]);
    }
    __syncthreads();

    // ---- per-block class partials (exact small ints), scaled by 1/100 ----
    if (tid < 160) {
        const int bq = tid / 10, cq = tid - bq * 10;
        float ssum = 0.f;
        for (int ch = 0; ch < nch; ++ch)
            ssum += h3buf[ch * 16 + bq] * wcs[ch * 10 + cq];
        atomicAdd(&out[bq * 10 + cq], ssum / 100.0f);
    }
}

extern "C" void kernel_launch(void* const* d_in, const int* in_sizes, int n_in,
                              void* d_out, int out_size, void* d_ws, size_t ws_size,
                              hipStream_t stream) {
    const float* x   = (const float*)d_in[0];
    const float* W1  = (const float*)d_in[1];
    const float* b1  = (const float*)d_in[2];
    const float* g1  = (const float*)d_in[3];
    const float* be1 = (const float*)d_in[4];
    const float* W2  = (const float*)d_in[5];
    const float* b2  = (const float*)d_in[6];
    const float* g2  = (const float*)d_in[7];
    const float* be2 = (const float*)d_in[8];
    const float* W3  = (const float*)d_in[9];
    const float* b3  = (const float*)d_in[10];
    const float* g3  = (const float*)d_in[11];
    const float* be3 = (const float*)d_in[12];
    const float* Wc  = (const float*)d_in[13];
    float* out  = (float*)d_out;
    float* w1q  = (float*)d_ws;                  // 250000 floats = 1 MB
    float* zrow = (float*)d_ws + 250000;         // 32 floats of zeros

    prep_w1<<<dim3(977), dim3(256), 0, stream>>>(W1, w1q, out, zrow);
    hdc_fused<<<dim3(1024), dim3(256), 0, stream>>>(
        x, w1q, b1, g1, be1, W2, b2, g2, be2, W3, b3, g3, be3, Wc, zrow, out);
}